// Round 1
// baseline (571.799 us; speedup 1.0000x reference)
//
#include <hip/hip_runtime.h>

#define T_LEN 16384
#define NB 8
#define CIN 64
#define MID 128
#define TT 32
#define HALO 4
#define TY (TT + 2*HALO)   // 40
#define TZ1 (TT + 4)       // 36
#define XPAD (TY + 1)      // 41
#define YPAD (TY + 1)      // 41
#define Z1PAD (TZ1 + 1)    // 37
#define Z2PAD (TT + 1)     // 33

// bufB layout (floats):
//  P0/P1: x_s [CIN][XPAD][2] = 5248 ; w_in chunk [16][129][2] @5248 = 4128  (9376)
//  P2   : z1  [MID][Z1PAD][2] = 9472
//  P4   : w_out chunk [32][65][2] = 4160 ; outs [2][CIN][33] @4160 = 4224   (8384)
#define BUFB_FLOATS 9472
#define WC_OFF 5248
#define WO_ROWPAD 65
#define OUTS_OFF 4160

__global__ __launch_bounds__(256, 2)
void cdc_fused(const float* __restrict__ x_re, const float* __restrict__ x_im,
               const float* __restrict__ w_in_re, const float* __restrict__ w_in_im,
               const float* __restrict__ b_in_re, const float* __restrict__ b_in_im,
               const float* __restrict__ alpha_in,
               const float* __restrict__ ln_in_w, const float* __restrict__ ln_in_b,
               const float* __restrict__ dw_re, const float* __restrict__ dw_im,
               const float* __restrict__ db_re, const float* __restrict__ db_im,
               const float* __restrict__ alpha_out,
               const float* __restrict__ ln_out_w, const float* __restrict__ ln_out_b,
               const float* __restrict__ w_out_re, const float* __restrict__ w_out_im,
               const float* __restrict__ b_out_re, const float* __restrict__ b_out_im,
               float* __restrict__ out)
{
    __shared__ __align__(16) float bufA[MID * YPAD * 2];   // 10496 floats
    __shared__ __align__(16) float bufB[BUFB_FLOATS];      // 9472 floats
    __shared__ float stats[TY][4];

    const int tid = threadIdx.x;
    const int b    = blockIdx.x >> 9;        // 512 tiles per batch
    const int tile = blockIdx.x & 511;
    const int t0 = tile * TT;

    const float* __restrict__ xr_base = x_re + (size_t)b * CIN * T_LEN;
    const float* __restrict__ xi_base = x_im + (size_t)b * CIN * T_LEN;

    // ---------------- P0: stage x tile (halo, zero-padded) ----------------
    for (int i = tid; i < CIN * TY; i += 256) {
        int k = i / TY;
        int col = i - k * TY;
        int gt = t0 - HALO + col;
        float vr = 0.f, vi = 0.f;
        if (gt >= 0 && gt < T_LEN) {
            vr = xr_base[k * T_LEN + gt];
            vi = xi_base[k * T_LEN + gt];
        }
        bufB[(k * XPAD + col) * 2 + 0] = vr;
        bufB[(k * XPAD + col) * 2 + 1] = vi;
    }

    const int c = tid & 127;
    const int half = tid >> 7;     // 0/1
    const int col0 = half * 20;

    // ---------------- P1: complex pointwise-in (y = W_in x + b) ----------------
    float accR[20], accI[20];
    {
        float bR = b_in_re[c], bI = b_in_im[c];
        #pragma unroll
        for (int j = 0; j < 20; ++j) { accR[j] = bR; accI[j] = bI; }
    }
    for (int kc = 0; kc < 4; ++kc) {
        __syncthreads();
        // stage transposed weight chunk: k in [16*kc, 16*kc+16)
        for (int i = tid; i < 16 * 128; i += 256) {
            int kk = i & 15;
            int cc = i >> 4;
            int gk = kc * 16 + kk;
            bufB[WC_OFF + (kk * 129 + cc) * 2 + 0] = w_in_re[cc * 64 + gk];
            bufB[WC_OFF + (kk * 129 + cc) * 2 + 1] = w_in_im[cc * 64 + gk];
        }
        __syncthreads();
        for (int kk = 0; kk < 16; ++kk) {
            int k = kc * 16 + kk;
            float2 w2 = *(const float2*)&bufB[WC_OFF + (kk * 129 + c) * 2];
            const float* xr0 = &bufB[(k * XPAD + col0) * 2];
            #pragma unroll
            for (int j = 0; j < 20; ++j) {
                float2 x2 = *(const float2*)(xr0 + 2 * j);
                accR[j] += w2.x * x2.x - w2.y * x2.y;
                accI[j] += w2.x * x2.y + w2.y * x2.x;
            }
        }
    }
    // PReLU(alpha_in), stash to bufA
    {
        float a = alpha_in[0];
        #pragma unroll
        for (int j = 0; j < 20; ++j) {
            float vr = accR[j]; vr = (vr >= 0.f) ? vr : a * vr;
            float vi = accI[j]; vi = (vi >= 0.f) ? vi : a * vi;
            bufA[(c * YPAD + col0 + j) * 2 + 0] = vr;
            bufA[(c * YPAD + col0 + j) * 2 + 1] = vi;
        }
    }
    __syncthreads();
    // LN-in stats over channels (per column)
    {
        int sub = tid & 7;
        for (int col = tid >> 3; col < TY; col += 32) {
            float sr = 0.f, si = 0.f, qr = 0.f, qi = 0.f;
            #pragma unroll
            for (int m = 0; m < 16; ++m) {
                int cc = sub + (m << 3);
                float2 v = *(const float2*)&bufA[(cc * YPAD + col) * 2];
                sr += v.x; qr += v.x * v.x;
                si += v.y; qi += v.y * v.y;
            }
            #pragma unroll
            for (int off = 1; off < 8; off <<= 1) {
                sr += __shfl_xor(sr, off);
                si += __shfl_xor(si, off);
                qr += __shfl_xor(qr, off);
                qi += __shfl_xor(qi, off);
            }
            if (sub == 0) {
                float mur = sr * 0.0078125f, mui = si * 0.0078125f;
                float vvr = qr * 0.0078125f - mur * mur;
                float vvi = qi * 0.0078125f - mui * mui;
                stats[col][0] = mur;
                stats[col][1] = rsqrtf(vvr + 1e-5f);
                stats[col][2] = mui;
                stats[col][3] = rsqrtf(vvi + 1e-5f);
            }
        }
    }
    __syncthreads();
    // LN-in apply (+ zero halo cols outside [0,T) -> conv zero-padding)
    {
        float lw = ln_in_w[c], lb = ln_in_b[c];
        #pragma unroll
        for (int j = 0; j < 20; ++j) {
            int col = col0 + j;
            int gt = t0 - HALO + col;
            bool valid = (gt >= 0) && (gt < T_LEN);
            float2 v = *(const float2*)&bufA[(c * YPAD + col) * 2];
            float vr = valid ? ((v.x - stats[col][0]) * stats[col][1] * lw + lb) : 0.f;
            float vi = valid ? ((v.y - stats[col][2]) * stats[col][3] * lw + lb) : 0.f;
            bufA[(c * YPAD + col) * 2 + 0] = vr;
            bufA[(c * YPAD + col) * 2 + 1] = vi;
        }
    }
    __syncthreads();
    // ---------------- P2: depthwise complex dconv layer 0 (y -> z1) ----------------
    {
        float w1r0 = dw_re[c*3+0], w1r1 = dw_re[c*3+1], w1r2 = dw_re[c*3+2];
        float w1i0 = dw_im[c*3+0], w1i1 = dw_im[c*3+1], w1i2 = dw_im[c*3+2];
        float dbr = db_re[c], dbi = db_im[c];
        const float* yb = &bufA[(c * YPAD) * 2];
        for (int j = half * 18; j < half * 18 + 18; ++j) {
            int gt = t0 - 2 + j;
            float2 y0 = *(const float2*)(yb + 2 * j);
            float2 y1 = *(const float2*)(yb + 2 * (j + 2));
            float2 y2 = *(const float2*)(yb + 2 * (j + 4));
            float zr = dbr + w1r0*y0.x - w1i0*y0.y + w1r1*y1.x - w1i1*y1.y + w1r2*y2.x - w1i2*y2.y;
            float zi = dbi + w1r0*y0.y + w1i0*y0.x + w1r1*y1.y + w1i1*y1.x + w1r2*y2.y + w1i2*y2.x;
            bool valid = (gt >= 0) && (gt < T_LEN);
            bufB[(c * Z1PAD + j) * 2 + 0] = valid ? zr : 0.f;
            bufB[(c * Z1PAD + j) * 2 + 1] = valid ? zi : 0.f;
        }
    }
    __syncthreads();
    // ---------------- P3: dconv layer 1 (z1 -> z2) + PReLU(alpha_out) ----------------
    {
        float w2r0 = dw_re[384 + c*3+0], w2r1 = dw_re[384 + c*3+1], w2r2 = dw_re[384 + c*3+2];
        float w2i0 = dw_im[384 + c*3+0], w2i1 = dw_im[384 + c*3+1], w2i2 = dw_im[384 + c*3+2];
        float dbr = db_re[128 + c], dbi = db_im[128 + c];
        float a = alpha_out[0];
        const float* zb = &bufB[(c * Z1PAD) * 2];
        for (int m = half * 16; m < half * 16 + 16; ++m) {
            float2 z0 = *(const float2*)(zb + 2 * m);
            float2 z1v = *(const float2*)(zb + 2 * (m + 2));
            float2 z2v = *(const float2*)(zb + 2 * (m + 4));
            float zr = dbr + w2r0*z0.x - w2i0*z0.y + w2r1*z1v.x - w2i1*z1v.y + w2r2*z2v.x - w2i2*z2v.y;
            float zi = dbi + w2r0*z0.y + w2i0*z0.x + w2r1*z1v.y + w2i1*z1v.x + w2r2*z2v.y + w2i2*z2v.x;
            zr = (zr >= 0.f) ? zr : a * zr;
            zi = (zi >= 0.f) ? zi : a * zi;
            bufA[(c * Z2PAD + m) * 2 + 0] = zr;
            bufA[(c * Z2PAD + m) * 2 + 1] = zi;
        }
    }
    __syncthreads();
    // LN-out stats (32 cols, Z2PAD stride)
    {
        int sub = tid & 7;
        for (int col = tid >> 3; col < TT; col += 32) {
            float sr = 0.f, si = 0.f, qr = 0.f, qi = 0.f;
            #pragma unroll
            for (int m = 0; m < 16; ++m) {
                int cc = sub + (m << 3);
                float2 v = *(const float2*)&bufA[(cc * Z2PAD + col) * 2];
                sr += v.x; qr += v.x * v.x;
                si += v.y; qi += v.y * v.y;
            }
            #pragma unroll
            for (int off = 1; off < 8; off <<= 1) {
                sr += __shfl_xor(sr, off);
                si += __shfl_xor(si, off);
                qr += __shfl_xor(qr, off);
                qi += __shfl_xor(qi, off);
            }
            if (sub == 0) {
                float mur = sr * 0.0078125f, mui = si * 0.0078125f;
                float vvr = qr * 0.0078125f - mur * mur;
                float vvi = qi * 0.0078125f - mui * mui;
                stats[col][0] = mur;
                stats[col][1] = rsqrtf(vvr + 1e-5f);
                stats[col][2] = mui;
                stats[col][3] = rsqrtf(vvi + 1e-5f);
            }
        }
    }
    __syncthreads();
    // LN-out apply
    {
        float lw = ln_out_w[c], lb = ln_out_b[c];
        for (int m = half * 16; m < half * 16 + 16; ++m) {
            float2 v = *(const float2*)&bufA[(c * Z2PAD + m) * 2];
            float vr = (v.x - stats[m][0]) * stats[m][1] * lw + lb;
            float vi = (v.y - stats[m][2]) * stats[m][3] * lw + lb;
            bufA[(c * Z2PAD + m) * 2 + 0] = vr;
            bufA[(c * Z2PAD + m) * 2 + 1] = vi;
        }
    }
    __syncthreads();
    // ---------------- P4: complex pointwise-out + bias ----------------
    const int o = tid & 63;
    const int cg = tid >> 6;       // 0..3
    const int oc0 = cg * 8;
    float oR[8], oI[8];
    {
        float bR = b_out_re[o], bI = b_out_im[o];
        #pragma unroll
        for (int j = 0; j < 8; ++j) { oR[j] = bR; oI[j] = bI; }
    }
    for (int cc4 = 0; cc4 < 4; ++cc4) {
        __syncthreads();
        for (int i = tid; i < 32 * 64; i += 256) {
            int ccc = i & 31;
            int oo = i >> 5;
            bufB[(ccc * WO_ROWPAD + oo) * 2 + 0] = w_out_re[oo * 128 + cc4 * 32 + ccc];
            bufB[(ccc * WO_ROWPAD + oo) * 2 + 1] = w_out_im[oo * 128 + cc4 * 32 + ccc];
        }
        __syncthreads();
        for (int ccc = 0; ccc < 32; ++ccc) {
            int cf = cc4 * 32 + ccc;
            float2 w2 = *(const float2*)&bufB[(ccc * WO_ROWPAD + o) * 2];
            const float* z0p = &bufA[(cf * Z2PAD + oc0) * 2];
            #pragma unroll
            for (int j = 0; j < 8; ++j) {
                float2 z = *(const float2*)(z0p + 2 * j);
                oR[j] += w2.x * z.x - w2.y * z.y;
                oI[j] += w2.x * z.y + w2.y * z.x;
            }
        }
    }
    // bounce to LDS for coalesced store
    #pragma unroll
    for (int j = 0; j < 8; ++j) {
        bufB[OUTS_OFF + 0 * (CIN * 33) + o * 33 + oc0 + j] = oR[j];
        bufB[OUTS_OFF + 1 * (CIN * 33) + o * 33 + oc0 + j] = oI[j];
    }
    __syncthreads();
    // ---------------- store + residual ----------------
    {
        const size_t plane = (size_t)NB * CIN * T_LEN;
        float* outR = out + (size_t)b * CIN * T_LEN;
        float* outI = outR + plane;
        for (int i = tid; i < CIN * TT; i += 256) {
            int oo = i >> 5;
            int colx = i & 31;
            int gt = t0 + colx;
            float xr = xr_base[oo * T_LEN + gt];
            float xi = xi_base[oo * T_LEN + gt];
            outR[oo * T_LEN + gt] = bufB[OUTS_OFF + oo * 33 + colx] + xr;
            outI[oo * T_LEN + gt] = bufB[OUTS_OFF + CIN * 33 + oo * 33 + colx] + xi;
        }
    }
}

extern "C" void kernel_launch(void* const* d_in, const int* in_sizes, int n_in,
                              void* d_out, int out_size, void* d_ws, size_t ws_size,
                              hipStream_t stream) {
    (void)in_sizes; (void)n_in; (void)d_ws; (void)ws_size; (void)out_size;
    const float* a0  = (const float*)d_in[0];
    const float* a1  = (const float*)d_in[1];
    const float* a2  = (const float*)d_in[2];
    const float* a3  = (const float*)d_in[3];
    const float* a4  = (const float*)d_in[4];
    const float* a5  = (const float*)d_in[5];
    const float* a6  = (const float*)d_in[6];
    const float* a7  = (const float*)d_in[7];
    const float* a8  = (const float*)d_in[8];
    const float* a9  = (const float*)d_in[9];
    const float* a10 = (const float*)d_in[10];
    const float* a11 = (const float*)d_in[11];
    const float* a12 = (const float*)d_in[12];
    const float* a13 = (const float*)d_in[13];
    const float* a14 = (const float*)d_in[14];
    const float* a15 = (const float*)d_in[15];
    const float* a16 = (const float*)d_in[16];
    const float* a17 = (const float*)d_in[17];
    const float* a18 = (const float*)d_in[18];
    const float* a19 = (const float*)d_in[19];
    dim3 grid(NB * (T_LEN / TT));   // 8 * 512 = 4096
    dim3 block(256);
    hipLaunchKernelGGL(cdc_fused, grid, block, 0, stream,
        a0, a1, a2, a3, a4, a5, a6, a7, a8, a9,
        a10, a11, a12, a13, a14, a15, a16, a17, a18, a19,
        (float*)d_out);
}

// Round 2
// 148.278 us; speedup vs baseline: 3.8563x; 3.8563x over previous
//
#include <hip/hip_runtime.h>

#define T_LEN 16384
#define NBATCH 8
#define CINCH 64
#define MIDCH 128
#define TT 64
#define PLANE (NBATCH * CINCH * T_LEN)

typedef __attribute__((ext_vector_type(8))) short short8;
typedef __attribute__((ext_vector_type(4))) float f32x4;

union fragu { short8 s; __bf16 h[8]; };

// ---- LDS byte offsets (phased reuse; total 73728 B -> 2 blocks/CU) ----
#define XR_OFF     0        // bf16 [80 cols][64 ch] swizzled, 10240 B
#define XI_OFF     10240    // 10240 B
#define PART1_OFF  20480    // f32 [4][80][4], 5120 B
#define STATS1_OFF 38912    // f32 [80][5], 1600 B (inside future Z1 region)
#define Y_OFF      0        // u32(bf16 pair) [128 ch][76 cols], 38912 B
#define Z1_OFF     38912    // u32 [128 ch][68 cols], 34816 B -> ends 73728
#define PART2_OFF  0        // f32 [4][64][4], 4096 B
#define STATS2_OFF 4096     // f32 [64][5], 1280 B
#define ZR_OFF     38912    // bf16 [64 cols][128 ch] swizzled, 16384 B
#define ZI_OFF     55296    // 16384 B
#define LDS_BYTES  73728

__device__ __forceinline__ unsigned pk2(float a, float b) {
    unsigned short ua = __builtin_bit_cast(unsigned short, (__bf16)a);
    unsigned short ub = __builtin_bit_cast(unsigned short, (__bf16)b);
    return (unsigned)ua | ((unsigned)ub << 16);
}
__device__ __forceinline__ float lo2f(unsigned u) { unsigned v = u << 16; return __builtin_bit_cast(float, v); }
__device__ __forceinline__ float hi2f(unsigned u) { unsigned v = u & 0xffff0000u; return __builtin_bit_cast(float, v); }

__global__ __launch_bounds__(256, 2)
void cdc_mfma(const float* __restrict__ x_re, const float* __restrict__ x_im,
              const float* __restrict__ w_in_re, const float* __restrict__ w_in_im,
              const float* __restrict__ b_in_re, const float* __restrict__ b_in_im,
              const float* __restrict__ alpha_in,
              const float* __restrict__ ln_in_w, const float* __restrict__ ln_in_b,
              const float* __restrict__ dw_re, const float* __restrict__ dw_im,
              const float* __restrict__ db_re, const float* __restrict__ db_im,
              const float* __restrict__ alpha_out,
              const float* __restrict__ ln_out_w, const float* __restrict__ ln_out_b,
              const float* __restrict__ w_out_re, const float* __restrict__ w_out_im,
              const float* __restrict__ b_out_re, const float* __restrict__ b_out_im,
              float* __restrict__ out)
{
    __shared__ __align__(16) unsigned char LDS[LDS_BYTES];
    unsigned char* ldsb = LDS;

    const int tid = threadIdx.x;
    const int w  = tid >> 6;       // wave 0..3
    const int l  = tid & 63;       // lane
    const int li = l & 15;
    const int u  = l >> 4;

    const int b    = blockIdx.x >> 8;     // 256 tiles per batch
    const int tile = blockIdx.x & 255;
    const int t0   = tile * TT;

    const float* xr_base = x_re + (size_t)b * CINCH * T_LEN;
    const float* xi_base = x_im + (size_t)b * CINCH * T_LEN;

    // ================= P1: stage x -> XR/XI (bf16, [col][ch] swizzled) ======
    for (int i = 0; i < 16; ++i) {
        int ch = w + 4 * i;
        int cy = l;                        // cols 0..63
        int gt = t0 - 4 + cy;
        float vr = 0.f, vi = 0.f;
        if (gt >= 0 && gt < T_LEN) { vr = xr_base[ch * T_LEN + gt]; vi = xi_base[ch * T_LEN + gt]; }
        int sw = ((ch + 8 * cy) & 63) * 2;
        *(__bf16*)(ldsb + XR_OFF + cy * 128 + sw) = (__bf16)vr;
        *(__bf16*)(ldsb + XI_OFF + cy * 128 + sw) = (__bf16)vi;
    }
    for (int p = 0; p < 2; ++p) {          // cols 64..71
        int idx = p * 256 + tid;
        int ch = idx >> 3;
        int cy = 64 + (idx & 7);
        int gt = t0 - 4 + cy;
        float vr = 0.f, vi = 0.f;
        if (gt >= 0 && gt < T_LEN) { vr = xr_base[ch * T_LEN + gt]; vi = xi_base[ch * T_LEN + gt]; }
        int sw = ((ch + 8 * cy) & 63) * 2;
        *(__bf16*)(ldsb + XR_OFF + cy * 128 + sw) = (__bf16)vr;
        *(__bf16*)(ldsb + XI_OFF + cy * 128 + sw) = (__bf16)vi;
    }
    for (int p = 0; p < 2; ++p) {          // zero-pad cols 72..79
        int idx = p * 256 + tid;
        int ch = idx >> 3;
        int cy = 72 + (idx & 7);
        int sw = ((ch + 8 * cy) & 63) * 2;
        *(__bf16*)(ldsb + XR_OFF + cy * 128 + sw) = (__bf16)0.f;
        *(__bf16*)(ldsb + XI_OFF + cy * 128 + sw) = (__bf16)0.f;
    }
    __syncthreads();

    // ================= P2: GEMM-in (MFMA), y = W_in * x + b ================
    fragu fr[2][2], fim[2][2], fng[2][2];
    #pragma unroll
    for (int mt2 = 0; mt2 < 2; ++mt2) {
        int row = (2 * w + mt2) * 16 + li;
        #pragma unroll
        for (int ks = 0; ks < 2; ++ks) {
            int k0 = ks * 32 + u * 8;
            const float* pr = w_in_re + row * 64 + k0;
            const float* pi = w_in_im + row * 64 + k0;
            #pragma unroll
            for (int j = 0; j < 8; ++j) {
                float vr = pr[j], vi = pi[j];
                fr[mt2][ks].h[j]  = (__bf16)vr;
                fim[mt2][ks].h[j] = (__bf16)vi;
                fng[mt2][ks].h[j] = (__bf16)(-vi);
            }
        }
    }
    f32x4 aR[2][5], aI[2][5];
    #pragma unroll
    for (int mt2 = 0; mt2 < 2; ++mt2) {
        int chb = (2 * w + mt2) * 16 + u * 4;
        f32x4 br, bi2;
        #pragma unroll
        for (int r = 0; r < 4; ++r) { br[r] = b_in_re[chb + r]; bi2[r] = b_in_im[chb + r]; }
        #pragma unroll
        for (int nt = 0; nt < 5; ++nt) { aR[mt2][nt] = br; aI[mt2][nt] = bi2; }
    }
    #pragma unroll
    for (int nt = 0; nt < 5; ++nt) {
        int col = nt * 16 + li;
        int rowb = col * 128;
        int sta = ((u * 8      + 8 * col) & 63) * 2;
        int stb = ((u * 8 + 32 + 8 * col) & 63) * 2;
        short8 xr0 = *(const short8*)(ldsb + XR_OFF + rowb + sta);
        short8 xr1 = *(const short8*)(ldsb + XR_OFF + rowb + stb);
        short8 xi0 = *(const short8*)(ldsb + XI_OFF + rowb + sta);
        short8 xi1 = *(const short8*)(ldsb + XI_OFF + rowb + stb);
        #pragma unroll
        for (int mt2 = 0; mt2 < 2; ++mt2) {
            aR[mt2][nt] = __builtin_amdgcn_mfma_f32_16x16x32_bf16(fr[mt2][0].s,  xr0, aR[mt2][nt], 0, 0, 0);
            aR[mt2][nt] = __builtin_amdgcn_mfma_f32_16x16x32_bf16(fr[mt2][1].s,  xr1, aR[mt2][nt], 0, 0, 0);
            aR[mt2][nt] = __builtin_amdgcn_mfma_f32_16x16x32_bf16(fng[mt2][0].s, xi0, aR[mt2][nt], 0, 0, 0);
            aR[mt2][nt] = __builtin_amdgcn_mfma_f32_16x16x32_bf16(fng[mt2][1].s, xi1, aR[mt2][nt], 0, 0, 0);
            aI[mt2][nt] = __builtin_amdgcn_mfma_f32_16x16x32_bf16(fr[mt2][0].s,  xi0, aI[mt2][nt], 0, 0, 0);
            aI[mt2][nt] = __builtin_amdgcn_mfma_f32_16x16x32_bf16(fr[mt2][1].s,  xi1, aI[mt2][nt], 0, 0, 0);
            aI[mt2][nt] = __builtin_amdgcn_mfma_f32_16x16x32_bf16(fim[mt2][0].s, xr0, aI[mt2][nt], 0, 0, 0);
            aI[mt2][nt] = __builtin_amdgcn_mfma_f32_16x16x32_bf16(fim[mt2][1].s, xr1, aI[mt2][nt], 0, 0, 0);
        }
    }

    // PReLU(alpha_in) in regs, then per-column partial sums for LN-in
    {
        float a1 = alpha_in[0];
        #pragma unroll
        for (int mt2 = 0; mt2 < 2; ++mt2)
            #pragma unroll
            for (int nt = 0; nt < 5; ++nt)
                #pragma unroll
                for (int r = 0; r < 4; ++r) {
                    float vr = aR[mt2][nt][r]; aR[mt2][nt][r] = vr >= 0.f ? vr : a1 * vr;
                    float vi = aI[mt2][nt][r]; aI[mt2][nt][r] = vi >= 0.f ? vi : a1 * vi;
                }
    }
    #pragma unroll
    for (int nt = 0; nt < 5; ++nt) {
        float sr = 0.f, qr = 0.f, si = 0.f, qi = 0.f;
        #pragma unroll
        for (int mt2 = 0; mt2 < 2; ++mt2)
            #pragma unroll
            for (int r = 0; r < 4; ++r) {
                float vr = aR[mt2][nt][r], vi = aI[mt2][nt][r];
                sr += vr; qr += vr * vr; si += vi; qi += vi * vi;
            }
        sr += __shfl_xor(sr, 16); sr += __shfl_xor(sr, 32);
        qr += __shfl_xor(qr, 16); qr += __shfl_xor(qr, 32);
        si += __shfl_xor(si, 16); si += __shfl_xor(si, 32);
        qi += __shfl_xor(qi, 16); qi += __shfl_xor(qi, 32);
        if (u == 0) {
            int col = nt * 16 + li;
            f32x4 v; v[0] = sr; v[1] = qr; v[2] = si; v[3] = qi;
            *(f32x4*)(ldsb + PART1_OFF + (w * 80 + col) * 16) = v;
        }
    }
    __syncthreads();
    if (tid < 80) {
        float SR = 0.f, QR = 0.f, SI = 0.f, QI = 0.f;
        #pragma unroll
        for (int ww = 0; ww < 4; ++ww) {
            f32x4 v = *(const f32x4*)(ldsb + PART1_OFF + (ww * 80 + tid) * 16);
            SR += v[0]; QR += v[1]; SI += v[2]; QI += v[3];
        }
        float mur = SR * 0.0078125f, mui = SI * 0.0078125f;
        float rr = rsqrtf(QR * 0.0078125f - mur * mur + 1e-5f);
        float ri = rsqrtf(QI * 0.0078125f - mui * mui + 1e-5f);
        float* sp = (float*)(ldsb + STATS1_OFF + tid * 20);
        sp[0] = mur; sp[1] = rr; sp[2] = mui; sp[3] = ri;
    }
    __syncthreads();

    // ========== P4: LN-in apply + write Y (packed bf16 [ch][76]) ===========
    {
        float lw[2][4], lb[2][4];
        #pragma unroll
        for (int mt2 = 0; mt2 < 2; ++mt2) {
            int chb = (2 * w + mt2) * 16 + u * 4;
            #pragma unroll
            for (int r = 0; r < 4; ++r) { lw[mt2][r] = ln_in_w[chb + r]; lb[mt2][r] = ln_in_b[chb + r]; }
        }
        #pragma unroll
        for (int nt = 0; nt < 5; ++nt) {
            int col = nt * 16 + li;
            if (col < 72) {
                const float* sp = (const float*)(ldsb + STATS1_OFF + col * 20);
                float mur = sp[0], rr = sp[1], mui = sp[2], ri = sp[3];
                int gt = t0 - 4 + col;
                bool valid = (gt >= 0) && (gt < T_LEN);
                #pragma unroll
                for (int mt2 = 0; mt2 < 2; ++mt2) {
                    int chb = (2 * w + mt2) * 16 + u * 4;
                    #pragma unroll
                    for (int r = 0; r < 4; ++r) {
                        float yr = valid ? ((aR[mt2][nt][r] - mur) * rr * lw[mt2][r] + lb[mt2][r]) : 0.f;
                        float yi = valid ? ((aI[mt2][nt][r] - mui) * ri * lw[mt2][r] + lb[mt2][r]) : 0.f;
                        *(unsigned*)(ldsb + Y_OFF + ((chb + r) * 76 + col) * 4) = pk2(yr, yi);
                    }
                }
            }
        }
    }
    __syncthreads();

    // ================= P5: depthwise complex dconv layer 0 =================
    {
        int cb = w * 32;
        #pragma unroll 4
        for (int i = 0; i < 32; ++i) {
            int ch = cb + i;
            float w1r0 = dw_re[ch*3+0], w1r1 = dw_re[ch*3+1], w1r2 = dw_re[ch*3+2];
            float w1i0 = dw_im[ch*3+0], w1i1 = dw_im[ch*3+1], w1i2 = dw_im[ch*3+2];
            float dbr = db_re[ch], dbi = db_im[ch];
            const unsigned* yrow = (const unsigned*)(ldsb + Y_OFF + ch * 76 * 4);
            int zc = l;
            unsigned y0 = yrow[zc], y1 = yrow[zc + 2], y2 = yrow[zc + 4];
            float y0r = lo2f(y0), y0i = hi2f(y0);
            float y1r = lo2f(y1), y1i = hi2f(y1);
            float y2r = lo2f(y2), y2i = hi2f(y2);
            float zr = dbr + w1r0*y0r - w1i0*y0i + w1r1*y1r - w1i1*y1i + w1r2*y2r - w1i2*y2i;
            float zi = dbi + w1r0*y0i + w1i0*y0r + w1r1*y1i + w1i1*y1r + w1r2*y2i + w1i2*y2r;
            int gt1 = t0 - 2 + zc;
            bool valid = (gt1 >= 0) && (gt1 < T_LEN);
            *(unsigned*)(ldsb + Z1_OFF + (ch * 68 + zc) * 4) = valid ? pk2(zr, zi) : 0u;
        }
        for (int p = 0; p < 2; ++p) {      // tail zc 64..67
            int idx = p * 256 + tid;
            int ch = idx & 127;
            int zc = 64 + (idx >> 7);
            float w1r0 = dw_re[ch*3+0], w1r1 = dw_re[ch*3+1], w1r2 = dw_re[ch*3+2];
            float w1i0 = dw_im[ch*3+0], w1i1 = dw_im[ch*3+1], w1i2 = dw_im[ch*3+2];
            float dbr = db_re[ch], dbi = db_im[ch];
            const unsigned* yrow = (const unsigned*)(ldsb + Y_OFF + ch * 76 * 4);
            unsigned y0 = yrow[zc], y1 = yrow[zc + 2], y2 = yrow[zc + 4];
            float y0r = lo2f(y0), y0i = hi2f(y0);
            float y1r = lo2f(y1), y1i = hi2f(y1);
            float y2r = lo2f(y2), y2i = hi2f(y2);
            float zr = dbr + w1r0*y0r - w1i0*y0i + w1r1*y1r - w1i1*y1i + w1r2*y2r - w1i2*y2i;
            float zi = dbi + w1r0*y0i + w1i0*y0r + w1r1*y1i + w1i1*y1r + w1r2*y2i + w1i2*y2r;
            int gt1 = t0 - 2 + zc;
            bool valid = (gt1 >= 0) && (gt1 < T_LEN);
            *(unsigned*)(ldsb + Z1_OFF + (ch * 68 + zc) * 4) = valid ? pk2(zr, zi) : 0u;
        }
    }
    __syncthreads();

    // ====== P6: dconv layer 1 + PReLU(alpha_out) + LN-out partials =========
    float z2r[32], z2i[32];
    {
        int cb = w * 32;
        int c2 = l;
        float a2 = alpha_out[0];
        float sr = 0.f, qr = 0.f, si = 0.f, qi = 0.f;
        #pragma unroll
        for (int i = 0; i < 32; ++i) {
            int ch = cb + i;
            float w2r0 = dw_re[384+ch*3+0], w2r1 = dw_re[384+ch*3+1], w2r2 = dw_re[384+ch*3+2];
            float w2i0 = dw_im[384+ch*3+0], w2i1 = dw_im[384+ch*3+1], w2i2 = dw_im[384+ch*3+2];
            float dbr = db_re[128+ch], dbi = db_im[128+ch];
            const unsigned* zrow = (const unsigned*)(ldsb + Z1_OFF + ch * 68 * 4);
            unsigned a0 = zrow[c2], a1 = zrow[c2 + 2], a2v = zrow[c2 + 4];
            float z0r = lo2f(a0), z0i = hi2f(a0);
            float z1r = lo2f(a1), z1i = hi2f(a1);
            float z2rr = lo2f(a2v), z2ii = hi2f(a2v);
            float zr = dbr + w2r0*z0r - w2i0*z0i + w2r1*z1r - w2i1*z1i + w2r2*z2rr - w2i2*z2ii;
            float zi = dbi + w2r0*z0i + w2i0*z0r + w2r1*z1i + w2i1*z1r + w2r2*z2ii + w2i2*z2rr;
            zr = zr >= 0.f ? zr : a2 * zr;
            zi = zi >= 0.f ? zi : a2 * zi;
            z2r[i] = zr; z2i[i] = zi;
            sr += zr; qr += zr * zr; si += zi; qi += zi * zi;
        }
        f32x4 v; v[0] = sr; v[1] = qr; v[2] = si; v[3] = qi;
        *(f32x4*)(ldsb + PART2_OFF + (w * 64 + c2) * 16) = v;
    }
    __syncthreads();
    if (tid < 64) {
        float SR = 0.f, QR = 0.f, SI = 0.f, QI = 0.f;
        #pragma unroll
        for (int ww = 0; ww < 4; ++ww) {
            f32x4 v = *(const f32x4*)(ldsb + PART2_OFF + (ww * 64 + tid) * 16);
            SR += v[0]; QR += v[1]; SI += v[2]; QI += v[3];
        }
        float mur = SR * 0.0078125f, mui = SI * 0.0078125f;
        float rr = rsqrtf(QR * 0.0078125f - mur * mur + 1e-5f);
        float ri = rsqrtf(QI * 0.0078125f - mui * mui + 1e-5f);
        float* sp = (float*)(ldsb + STATS2_OFF + tid * 20);
        sp[0] = mur; sp[1] = rr; sp[2] = mui; sp[3] = ri;
    }
    __syncthreads();

    // ========== P8: LN-out apply + write ZR/ZI ([col][ch] swizzled) ========
    {
        int c2 = l;
        int cb = w * 32;
        const float* sp = (const float*)(ldsb + STATS2_OFF + c2 * 20);
        float mur = sp[0], rr = sp[1], mui = sp[2], ri = sp[3];
        #pragma unroll
        for (int i = 0; i < 32; ++i) {
            float lw = ln_out_w[cb + i], lb2 = ln_out_b[cb + i];
            z2r[i] = (z2r[i] - mur) * rr * lw + lb2;
            z2i[i] = (z2i[i] - mui) * ri * lw + lb2;
        }
        #pragma unroll
        for (int kb = 0; kb < 4; ++kb) {
            fragu hr, hi2;
            #pragma unroll
            for (int j = 0; j < 8; ++j) {
                hr.h[j]  = (__bf16)z2r[kb * 8 + j];
                hi2.h[j] = (__bf16)z2i[kb * 8 + j];
            }
            int st = ((cb + kb * 8 + 8 * c2) & 127) * 2;
            *(short8*)(ldsb + ZR_OFF + c2 * 256 + st) = hr.s;
            *(short8*)(ldsb + ZI_OFF + c2 * 256 + st) = hi2.s;
        }
    }
    __syncthreads();

    // ================= P9: GEMM-out (MFMA) + residual ======================
    fragu gr[4], gim[4], gng[4];
    {
        int o = w * 16 + li;
        #pragma unroll
        for (int ks = 0; ks < 4; ++ks) {
            int k0 = ks * 32 + u * 8;
            const float* pr = w_out_re + o * 128 + k0;
            const float* pi = w_out_im + o * 128 + k0;
            #pragma unroll
            for (int j = 0; j < 8; ++j) {
                float vr = pr[j], vi = pi[j];
                gr[ks].h[j]  = (__bf16)vr;
                gim[ks].h[j] = (__bf16)vi;
                gng[ks].h[j] = (__bf16)(-vi);
            }
        }
    }
    f32x4 oR[4], oI[4];
    {
        int ob = w * 16 + u * 4;
        f32x4 br, bi2;
        #pragma unroll
        for (int r = 0; r < 4; ++r) { br[r] = b_out_re[ob + r]; bi2[r] = b_out_im[ob + r]; }
        #pragma unroll
        for (int nt = 0; nt < 4; ++nt) { oR[nt] = br; oI[nt] = bi2; }
    }
    #pragma unroll
    for (int nt = 0; nt < 4; ++nt) {
        int col = nt * 16 + li;
        #pragma unroll
        for (int ks = 0; ks < 4; ++ks) {
            int k0 = ks * 32 + u * 8;
            int st = ((k0 + 8 * col) & 127) * 2;
            short8 zr8 = *(const short8*)(ldsb + ZR_OFF + col * 256 + st);
            short8 zi8 = *(const short8*)(ldsb + ZI_OFF + col * 256 + st);
            oR[nt] = __builtin_amdgcn_mfma_f32_16x16x32_bf16(gr[ks].s,  zr8, oR[nt], 0, 0, 0);
            oR[nt] = __builtin_amdgcn_mfma_f32_16x16x32_bf16(gng[ks].s, zi8, oR[nt], 0, 0, 0);
            oI[nt] = __builtin_amdgcn_mfma_f32_16x16x32_bf16(gr[ks].s,  zi8, oI[nt], 0, 0, 0);
            oI[nt] = __builtin_amdgcn_mfma_f32_16x16x32_bf16(gim[ks].s, zr8, oI[nt], 0, 0, 0);
        }
    }
    {
        int ob = w * 16 + u * 4;
        #pragma unroll
        for (int nt = 0; nt < 4; ++nt) {
            int col = nt * 16 + li;
            int gt = t0 + col;
            #pragma unroll
            for (int r = 0; r < 4; ++r) {
                size_t idx = ((size_t)b * CINCH + (ob + r)) * T_LEN + gt;
                out[idx]         = oR[nt][r] + x_re[idx];
                out[PLANE + idx] = oI[nt][r] + x_im[idx];
            }
        }
    }
}

extern "C" void kernel_launch(void* const* d_in, const int* in_sizes, int n_in,
                              void* d_out, int out_size, void* d_ws, size_t ws_size,
                              hipStream_t stream) {
    (void)in_sizes; (void)n_in; (void)d_ws; (void)ws_size; (void)out_size;
    dim3 grid(NBATCH * (T_LEN / TT));   // 8 * 256 = 2048
    dim3 block(256);
    hipLaunchKernelGGL(cdc_mfma, grid, block, 0, stream,
        (const float*)d_in[0],  (const float*)d_in[1],  (const float*)d_in[2],
        (const float*)d_in[3],  (const float*)d_in[4],  (const float*)d_in[5],
        (const float*)d_in[6],  (const float*)d_in[7],  (const float*)d_in[8],
        (const float*)d_in[9],  (const float*)d_in[10], (const float*)d_in[11],
        (const float*)d_in[12], (const float*)d_in[13], (const float*)d_in[14],
        (const float*)d_in[15], (const float*)d_in[16], (const float*)d_in[17],
        (const float*)d_in[18], (const float*)d_in[19], (float*)d_out);
}